// Round 5
// baseline (82.459 us; speedup 1.0000x reference)
//
#include <hip/hip_runtime.h>

#define HH 128
#define WW 128
// SW=16 cols/window, double-buffered: 40 float4 of asm-pinned state =
// 160 VGPR + ~30 overhead -> fits 256-VGPR cap with NO SPILLS (spills of
// inline-asm load dsts are silent corruption: compiler has no vmcnt model).

typedef float f4 __attribute__((ext_vector_type(4)));

// ---- inline-asm VMEM: compiler cannot split, sink, or reorder these ----
#define GLOAD(dst, ptr, OFF)                                                  \
    asm volatile("global_load_dwordx4 %0, %1, off offset:%2"                  \
                 : "=&v"(dst) : "v"(ptr), "n"(OFF) : "memory");

#define GSTORE(val, ptr, OFF)                                                 \
    asm volatile("global_store_dwordx4 %0, %1, off offset:%2"                 \
                 :: "v"(ptr), "v"(val), "n"(OFF) : "memory");

#define VMCNT(N)                                                              \
    asm volatile("s_waitcnt vmcnt(" #N ")" ::: "memory");                     \
    __builtin_amdgcn_sched_barrier(0);

// 4 x 16B per operand per window (16 cols)
#define LD4(P, s, ptr, WOFF)                                                  \
    GLOAD(P##s##0, ptr, (WOFF)+0)   GLOAD(P##s##1, ptr, (WOFF)+16)            \
    GLOAD(P##s##2, ptr, (WOFF)+32)  GLOAD(P##s##3, ptr, (WOFF)+48)

#define LD20(P, WOFF)                                                         \
    LD4(P, x, xp, WOFF) LD4(P, b, bp, WOFF) LD4(P, a, ap, WOFF)               \
    LD4(P, c, cp, WOFF) LD4(P, d, dp, WOFF)

#define ST4(P, WOFF)                                                          \
    GSTORE(P##x0, op, (WOFF)+0)   GSTORE(P##x1, op, (WOFF)+16)                \
    GSTORE(P##x2, op, (WOFF)+32)  GSTORE(P##x3, op, (WOFF)+48)

#define DECLBUF(P)                                                            \
    f4 P##x0,P##x1,P##x2,P##x3;                                               \
    f4 P##b0,P##b1,P##b2,P##b3;                                               \
    f4 P##a0,P##a1,P##a2,P##a3;                                               \
    f4 P##c0,P##c1,P##c2,P##c3;                                               \
    f4 P##d0,P##d1,P##d2,P##d3;

#define MUL4(a, b)                                                            \
    { (a)[0]*=(b)[0]; (a)[1]*=(b)[1]; (a)[2]*=(b)[2]; (a)[3]*=(b)[3]; }

#define FUSE(P)                                                               \
    MUL4(P##x0,P##b0) MUL4(P##x1,P##b1) MUL4(P##x2,P##b2) MUL4(P##x3,P##b3)

// One scan step: lgkm-only wait + raw s_barrier (no vmcnt drain — the
// in-flight prefetch loads/stores must stay outstanding). Parity-double-
// buffered 4-float LDS halo for the rows 63/64 wave boundary (validated r3).
#define STEP(xc, ac, cc, dc, par) do {                                        \
        float up = __shfl_up(hp, 1);                                          \
        float dn = __shfl_down(hp, 1);                                        \
        if (t == 63)  dn = halo[par][1];                                      \
        if (t == 64)  up = halo[par][0];                                      \
        if (t == 0)   up = 0.f;                                               \
        if (t == 127) dn = 0.f;                                               \
        const float h = (xc) + (ac) * up + (cc) * hp + (dc) * dn;             \
        if (t == 63) halo[(par) ^ 1][0] = h;                                  \
        if (t == 64) halo[(par) ^ 1][1] = h;                                  \
        asm volatile("s_waitcnt lgkmcnt(0)" ::: "memory");                    \
        __builtin_amdgcn_s_barrier();                                         \
        hp = h; (xc) = h;                                                     \
    } while (0)

#define STEP4(P, v)                                                           \
    STEP(P##x##v[0], P##a##v[0], P##c##v[0], P##d##v[0], 0);                  \
    STEP(P##x##v[1], P##a##v[1], P##c##v[1], P##d##v[1], 1);                  \
    STEP(P##x##v[2], P##a##v[2], P##c##v[2], P##d##v[2], 0);                  \
    STEP(P##x##v[3], P##a##v[3], P##c##v[3], P##d##v[3], 1);

#define SCAN16(P) STEP4(P,0) STEP4(P,1) STEP4(P,2) STEP4(P,3)

// 2 waves per (n,c) plane, 1 row per thread. Software pipeline: while
// scanning window w, window w+1's 20 loads are in flight. VMCNT(4) per
// window: 4 newest outstanding = previous window's stores; in-order drain
// means the 20 older loads are complete.
__global__ __launch_bounds__(128, 2) void gr2d_kernel(
    const float* __restrict__ X, const float* __restrict__ Bm,
    const float* __restrict__ G1, const float* __restrict__ G2,
    const float* __restrict__ G3, float* __restrict__ Out)
{
    const int t = threadIdx.x;                               // row 0..127
    const size_t rb = (size_t)blockIdx.x * (HH * WW) + (size_t)t * WW;
    const float* xp = X  + rb;
    const float* bp = Bm + rb;
    const float* ap = G1 + rb;
    const float* cp = G2 + rb;
    const float* dp = G3 + rb;
    float*       op = Out + rb;

    __shared__ float halo[2][2];
    if (t == 0) { halo[0][0] = 0.f; halo[0][1] = 0.f; }
    __syncthreads();

    float hp = 0.f;
    DECLBUF(A)
    DECLBUF(B)

    // prologue: window 0 in flight
    LD20(A, 0)

    // w0 (scan A, prefetch B)
    VMCNT(0)  LD20(B, 64)   FUSE(A) SCAN16(A) ST4(A, 0)
    // w1 (scan B, prefetch A)
    VMCNT(4)  LD20(A, 128)  FUSE(B) SCAN16(B) ST4(B, 64)
    // w2
    VMCNT(4)  LD20(B, 192)  FUSE(A) SCAN16(A) ST4(A, 128)
    // w3
    VMCNT(4)  LD20(A, 256)  FUSE(B) SCAN16(B) ST4(B, 192)
    // w4
    VMCNT(4)  LD20(B, 320)  FUSE(A) SCAN16(A) ST4(A, 256)
    // w5
    VMCNT(4)  LD20(A, 384)  FUSE(B) SCAN16(B) ST4(B, 320)
    // w6
    VMCNT(4)  LD20(B, 448)  FUSE(A) SCAN16(A) ST4(A, 384)
    // w7 (scan B, no prefetch)
    VMCNT(4)  FUSE(B) SCAN16(B) ST4(B, 448)

    // drain asm stores before endpgm (compiler doesn't know about them)
    asm volatile("s_waitcnt vmcnt(0)" ::: "memory");
}

extern "C" void kernel_launch(void* const* d_in, const int* in_sizes, int n_in,
                              void* d_out, int out_size, void* d_ws, size_t ws_size,
                              hipStream_t stream) {
    const float* X  = (const float*)d_in[0];
    const float* Bm = (const float*)d_in[1];
    const float* G1 = (const float*)d_in[2];
    const float* G2 = (const float*)d_in[3];
    const float* G3 = (const float*)d_in[4];
    float* Out = (float*)d_out;

    const int planes = in_sizes[0] / (HH * WW);   // 8*96 = 768
    gr2d_kernel<<<dim3(planes), dim3(128), 0, stream>>>(X, Bm, G1, G2, G3, Out);
}

// Round 6
// 71.061 us; speedup vs baseline: 1.1604x; 1.1604x over previous
//
#include <hip/hip_runtime.h>

#define HH 128
#define WW 128
// SW=32 cols/window: every load is a full 128B line per row (no read amp).
// Single register buffer + STAGGERED prefetch of the next window (x, b, a,
// then c+d) timed against the scan's progressive register frees, so peak
// liveness is ~50 float4 = 200 VGPR (r4's 320-VGPR double-buffer overflowed
// the cap and spilled in-flight asm load dsts = silent corruption).

typedef float f4 __attribute__((ext_vector_type(4)));

// ---- inline-asm VMEM: compiler cannot split, sink, or reorder these ----
#define GLOAD(dst, ptr, OFF)                                                  \
    asm volatile("global_load_dwordx4 %0, %1, off offset:%2"                  \
                 : "=&v"(dst) : "v"(ptr), "n"(OFF) : "memory");

#define GSTORE(val, ptr, OFF)                                                 \
    asm volatile("global_store_dwordx4 %0, %1, off offset:%2"                 \
                 :: "v"(ptr), "v"(val), "n"(OFF) : "memory");

#define VMCNT(N)                                                              \
    asm volatile("s_waitcnt vmcnt(" #N ")" ::: "memory");                     \
    __builtin_amdgcn_sched_barrier(0);

// 8 x 16B = one full 128B line per row per operand per window
#define LD8(P, s, ptr, WOFF)                                                  \
    GLOAD(P##s##0, ptr, (WOFF)+0)   GLOAD(P##s##1, ptr, (WOFF)+16)            \
    GLOAD(P##s##2, ptr, (WOFF)+32)  GLOAD(P##s##3, ptr, (WOFF)+48)            \
    GLOAD(P##s##4, ptr, (WOFF)+64)  GLOAD(P##s##5, ptr, (WOFF)+80)            \
    GLOAD(P##s##6, ptr, (WOFF)+96)  GLOAD(P##s##7, ptr, (WOFF)+112)

#define ST4H1(P, WOFF)                                                        \
    GSTORE(P##x0, op, (WOFF)+0)   GSTORE(P##x1, op, (WOFF)+16)                \
    GSTORE(P##x2, op, (WOFF)+32)  GSTORE(P##x3, op, (WOFF)+48)

#define ST4H2(P, WOFF)                                                        \
    GSTORE(P##x4, op, (WOFF)+64)  GSTORE(P##x5, op, (WOFF)+80)                \
    GSTORE(P##x6, op, (WOFF)+96)  GSTORE(P##x7, op, (WOFF)+112)

#define DECLBUF(P)                                                            \
    f4 P##x0,P##x1,P##x2,P##x3,P##x4,P##x5,P##x6,P##x7;                       \
    f4 P##b0,P##b1,P##b2,P##b3,P##b4,P##b5,P##b6,P##b7;                       \
    f4 P##a0,P##a1,P##a2,P##a3,P##a4,P##a5,P##a6,P##a7;                       \
    f4 P##c0,P##c1,P##c2,P##c3,P##c4,P##c5,P##c6,P##c7;                       \
    f4 P##d0,P##d1,P##d2,P##d3,P##d4,P##d5,P##d6,P##d7;

#define MUL4(a, b)                                                            \
    { (a)[0]*=(b)[0]; (a)[1]*=(b)[1]; (a)[2]*=(b)[2]; (a)[3]*=(b)[3]; }

#define FUSE8(P)                                                              \
    MUL4(P##x0,P##b0) MUL4(P##x1,P##b1) MUL4(P##x2,P##b2) MUL4(P##x3,P##b3)   \
    MUL4(P##x4,P##b4) MUL4(P##x5,P##b5) MUL4(P##x6,P##b6) MUL4(P##x7,P##b7)

// One scan step (validated r3/r5): lgkm-only wait + raw s_barrier — no
// vmcnt drain, so the in-flight staggered prefetch stays outstanding.
#define STEP(xc, ac, cc, dc, par) do {                                        \
        float up = __shfl_up(hp, 1);                                          \
        float dn = __shfl_down(hp, 1);                                        \
        if (t == 63)  dn = halo[par][1];                                      \
        if (t == 64)  up = halo[par][0];                                      \
        if (t == 0)   up = 0.f;                                               \
        if (t == 127) dn = 0.f;                                               \
        const float h = (xc) + (ac) * up + (cc) * hp + (dc) * dn;             \
        if (t == 63) halo[(par) ^ 1][0] = h;                                  \
        if (t == 64) halo[(par) ^ 1][1] = h;                                  \
        asm volatile("s_waitcnt lgkmcnt(0)" ::: "memory");                    \
        __builtin_amdgcn_s_barrier();                                         \
        hp = h; (xc) = h;                                                     \
    } while (0)

#define STEP4(P, v)                                                           \
    STEP(P##x##v[0], P##a##v[0], P##c##v[0], P##d##v[0], 0);                  \
    STEP(P##x##v[1], P##a##v[1], P##c##v[1], P##d##v[1], 1);                  \
    STEP(P##x##v[2], P##a##v[2], P##c##v[2], P##d##v[2], 0);                  \
    STEP(P##x##v[3], P##a##v[3], P##c##v[3], P##d##v[3], 1);

// Scan window C (32 steps) while prefetching window N in 4 tranches timed
// to the register frees: b dies at FUSE; each STEP4 kills 3 f4 of a/c/d;
// x0..3 store at mid-window. Peak live = 50 f4.
#define WINDOW_PF(C, N, WOFF, NOFF)                                           \
    FUSE8(C)                                                                  \
    LD8(N, x, xp, NOFF)                                                       \
    STEP4(C,0) STEP4(C,1)                                                     \
    LD8(N, b, bp, NOFF)                                                       \
    STEP4(C,2) STEP4(C,3)                                                     \
    ST4H1(C, WOFF)                                                            \
    LD8(N, a, ap, NOFF)                                                       \
    STEP4(C,4) STEP4(C,5)                                                     \
    LD8(N, c, cp, NOFF) LD8(N, d, dp, NOFF)                                   \
    STEP4(C,6) STEP4(C,7)                                                     \
    ST4H2(C, WOFF)

#define WINDOW_LAST(C, WOFF)                                                  \
    FUSE8(C)                                                                  \
    STEP4(C,0) STEP4(C,1) STEP4(C,2) STEP4(C,3)                               \
    ST4H1(C, WOFF)                                                            \
    STEP4(C,4) STEP4(C,5) STEP4(C,6) STEP4(C,7)                               \
    ST4H2(C, WOFF)

// 2 waves per (n,c) plane, 1 row per thread (t = row). VMCNT(4) per window
// boundary: the 4 newest outstanding VMEM ops are the late store-half; vmcnt
// retires in issue order, so <=4 outstanding implies all 40 prefetch loads
// (older) have landed.
__global__ __launch_bounds__(128, 2) void gr2d_kernel(
    const float* __restrict__ X, const float* __restrict__ Bm,
    const float* __restrict__ G1, const float* __restrict__ G2,
    const float* __restrict__ G3, float* __restrict__ Out)
{
    const int t = threadIdx.x;                               // row 0..127
    const size_t rb = (size_t)blockIdx.x * (HH * WW) + (size_t)t * WW;
    const float* xp = X  + rb;
    const float* bp = Bm + rb;
    const float* ap = G1 + rb;
    const float* cp = G2 + rb;
    const float* dp = G3 + rb;
    float*       op = Out + rb;

    __shared__ float halo[2][2];
    if (t == 0) { halo[0][0] = 0.f; halo[0][1] = 0.f; }
    __syncthreads();

    float hp = 0.f;
    DECLBUF(A)
    DECLBUF(B)

    // prologue: window 0 fully in flight
    LD8(A, x, xp, 0) LD8(A, b, bp, 0) LD8(A, a, ap, 0)
    LD8(A, c, cp, 0) LD8(A, d, dp, 0)

    VMCNT(0)  WINDOW_PF(A, B, 0,   128)
    VMCNT(4)  WINDOW_PF(B, A, 128, 256)
    VMCNT(4)  WINDOW_PF(A, B, 256, 384)
    VMCNT(4)  WINDOW_LAST(B, 384)

    // drain asm stores before endpgm (compiler doesn't know about them)
    asm volatile("s_waitcnt vmcnt(0)" ::: "memory");
}

extern "C" void kernel_launch(void* const* d_in, const int* in_sizes, int n_in,
                              void* d_out, int out_size, void* d_ws, size_t ws_size,
                              hipStream_t stream) {
    const float* X  = (const float*)d_in[0];
    const float* Bm = (const float*)d_in[1];
    const float* G1 = (const float*)d_in[2];
    const float* G2 = (const float*)d_in[3];
    const float* G3 = (const float*)d_in[4];
    float* Out = (float*)d_out;

    const int planes = in_sizes[0] / (HH * WW);   // 8*96 = 768
    gr2d_kernel<<<dim3(planes), dim3(128), 0, stream>>>(X, Bm, G1, G2, G3, Out);
}